// Round 4
// baseline (315.601 us; speedup 1.0000x reference)
//
#include <hip/hip_runtime.h>
#include <math.h>

#define S_SEQ 1024
#define NHEAD 16
#define HDIM  64
#define BATCH 4

typedef __attribute__((ext_vector_type(8))) short bf16x8;
typedef __attribute__((ext_vector_type(4))) float f32x4;
typedef __attribute__((ext_vector_type(16))) float f32x16;

__device__ __forceinline__ float bf2f(unsigned short h) {
    union { unsigned u; float f; } un; un.u = ((unsigned)h) << 16; return un.f;
}
__device__ __forceinline__ unsigned short f2bf(float x) {
    union { float f; unsigned u; } un; un.f = x;
    unsigned r = un.u + 0x7FFFu + ((un.u >> 16) & 1u);
    return (unsigned short)(r >> 16);
}
__device__ __forceinline__ unsigned pack2bf(float a, float b) {
    return (unsigned)f2bf(a) | ((unsigned)f2bf(b) << 16);
}
__device__ __forceinline__ void glds16(const unsigned short* g, unsigned short* l) {
    __builtin_amdgcn_global_load_lds(
        (const __attribute__((address_space(1))) void*)g,
        (__attribute__((address_space(3))) void*)l, 16, 0, 0);
}

// ---------------------------------------------------------------------------
// Prep 1: fp32 -> bf16 flat conversion of hidden_states and dist_emb.
// ---------------------------------------------------------------------------
#define HS_F4 1048576   // 4*1024*1024 / 4
#define PE_F4 32752     // 2047*64 / 4
__global__ __launch_bounds__(256) void conv_kernel(
    const float* __restrict__ hs, const float* __restrict__ de,
    unsigned short* __restrict__ hsb, unsigned short* __restrict__ peb)
{
    int i = blockIdx.x * 256 + threadIdx.x;
    if (i < HS_F4) {
        float4 v = ((const float4*)hs)[i];
        uint2 o;
        o.x = pack2bf(v.x, v.y);
        o.y = pack2bf(v.z, v.w);
        *(uint2*)(hsb + 4 * (size_t)i) = o;
    } else if (i < HS_F4 + PE_F4) {
        int j = i - HS_F4;
        float4 v = ((const float4*)de)[j];
        uint2 o;
        o.x = pack2bf(v.x, v.y);
        o.y = pack2bf(v.z, v.w);
        *(uint2*)(peb + 4 * (size_t)j) = o;
    }
}

// ---------------------------------------------------------------------------
// Prep 2: transpose+convert Wq/Wk/Wv (fp32 [k][n]) -> bf16 WT [n][k].
// ---------------------------------------------------------------------------
__global__ __launch_bounds__(256) void wtrans_kernel(
    const float* __restrict__ Wq, const float* __restrict__ Wk,
    const float* __restrict__ Wv, unsigned short* __restrict__ wt)
{
    __shared__ float tl[64 * 67];
    const int which = blockIdx.z;
    const float* W = (which == 0) ? Wq : (which == 1) ? Wk : Wv;
    unsigned short* out = wt + (size_t)which * 1024 * 1024;
    const int k0 = blockIdx.x * 64, n0 = blockIdx.y * 64;
    const int t = threadIdx.x;

#pragma unroll
    for (int it = 0; it < 4; ++it) {
        int idx = t + it * 256;
        int kr = idx >> 4;
        int c4 = (idx & 15) << 2;
        float4 v = *(const float4*)(W + (size_t)(k0 + kr) * 1024 + n0 + c4);
        tl[kr * 67 + c4 + 0] = v.x; tl[kr * 67 + c4 + 1] = v.y;
        tl[kr * 67 + c4 + 2] = v.z; tl[kr * 67 + c4 + 3] = v.w;
    }
    __syncthreads();
#pragma unroll
    for (int it = 0; it < 2; ++it) {
        int idx = t + it * 256;
        int nr = idx >> 3;
        int k8 = (idx & 7) << 3;
        unsigned short r[8];
#pragma unroll
        for (int e = 0; e < 8; ++e) r[e] = f2bf(tl[(k8 + e) * 67 + nr]);
        uint4 o;
        o.x = (unsigned)r[0] | ((unsigned)r[1] << 16);
        o.y = (unsigned)r[2] | ((unsigned)r[3] << 16);
        o.z = (unsigned)r[4] | ((unsigned)r[5] << 16);
        o.w = (unsigned)r[6] | ((unsigned)r[7] << 16);
        *(uint4*)(out + (size_t)(n0 + nr) * 1024 + k0 + k8) = o;
    }
}

// ---------------------------------------------------------------------------
// QKV GEMM, m97-style (unchanged from R3). v written transposed [b,h,d,s].
// ---------------------------------------------------------------------------
__global__ __launch_bounds__(256, 3) void qkv_mfma_kernel(
    const unsigned short* __restrict__ hsb, const unsigned short* __restrict__ wt,
    const float* __restrict__ bq, const float* __restrict__ bk,
    const float* __restrict__ bv,
    unsigned short* __restrict__ qo, unsigned short* __restrict__ ko,
    unsigned short* __restrict__ vo)
{
    __shared__ unsigned short As[128 * 64];
    __shared__ unsigned short Bs[128 * 64];

    const int t = threadIdx.x;
    const int lane = t & 63, w = t >> 6;
    const int l16 = lane & 15, quad = lane >> 4;
    const int wm = w >> 1, wn = w & 1;
    const int lrow = lane >> 3, cs = lane & 7;
    const int n0 = blockIdx.x * 128, m0 = blockIdx.y * 128;
    const int which = blockIdx.z;
    const unsigned short* wts = wt + (size_t)which * 1024 * 1024;
    const float* bias = (which == 0) ? bq : (which == 1) ? bk : bv;

    f32x4 acc[4][4];
#pragma unroll
    for (int i = 0; i < 4; ++i)
#pragma unroll
        for (int j = 0; j < 4; ++j) acc[i][j] = (f32x4){0.f, 0.f, 0.f, 0.f};

    for (int kk = 0; kk < 1024; kk += 64) {
#pragma unroll
        for (int it = 0; it < 4; ++it) {
            int mrow = 32 * w + 8 * it + lrow;
            int kch = cs ^ (mrow & 7);
            glds16(hsb + (size_t)(m0 + mrow) * 1024 + kk + kch * 8,
                   &As[(32 * w + 8 * it) * 64]);
            glds16(wts + (size_t)(n0 + mrow) * 1024 + kk + kch * 8,
                   &Bs[(32 * w + 8 * it) * 64]);
        }
        __syncthreads();

        bf16x8 af[4][2], bf[4][2];
#pragma unroll
        for (int i = 0; i < 4; ++i) {
            int am = 64 * wm + 16 * i + l16;
            int base = am * 64;
            af[i][0] = *(bf16x8*)&As[base + ((quad ^ (am & 7)) << 3)];
            af[i][1] = *(bf16x8*)&As[base + (((quad + 4) ^ (am & 7)) << 3)];
        }
#pragma unroll
        for (int j = 0; j < 4; ++j) {
            int bn = 64 * wn + 16 * j + l16;
            int base = bn * 64;
            bf[j][0] = *(bf16x8*)&Bs[base + ((quad ^ (bn & 7)) << 3)];
            bf[j][1] = *(bf16x8*)&Bs[base + (((quad + 4) ^ (bn & 7)) << 3)];
        }
#pragma unroll
        for (int i = 0; i < 4; ++i)
#pragma unroll
            for (int j = 0; j < 4; ++j) {
                acc[i][j] = __builtin_amdgcn_mfma_f32_16x16x32_bf16(
                    af[i][0], bf[j][0], acc[i][j], 0, 0, 0);
                acc[i][j] = __builtin_amdgcn_mfma_f32_16x16x32_bf16(
                    af[i][1], bf[j][1], acc[i][j], 0, 0, 0);
            }
        __syncthreads();
    }

#pragma unroll
    for (int j = 0; j < 4; ++j) {
        int n = n0 + 64 * wn + 16 * j + l16;
        float bvv = bias[n];
        int hh = n >> 6, hd = n & 63;
#pragma unroll
        for (int i = 0; i < 4; ++i) {
            int mb = m0 + 64 * wm + 16 * i + 4 * quad;
            int bb = mb >> 10, s = mb & 1023;
            if (which == 2) {
                uint2 o;
                o.x = pack2bf(acc[i][j][0] + bvv, acc[i][j][1] + bvv);
                o.y = pack2bf(acc[i][j][2] + bvv, acc[i][j][3] + bvv);
                *(uint2*)(vo + ((size_t)(bb * NHEAD + hh) * HDIM + hd) * S_SEQ + s) = o;
            } else {
                unsigned short* out = (which == 0) ? qo : ko;
#pragma unroll
                for (int r = 0; r < 4; ++r)
                    out[((size_t)(bb * NHEAD + hh) * S_SEQ + s + r) * HDIM + hd] =
                        f2bf(acc[i][j][r] + bvv);
            }
        }
    }
}

// ---------------------------------------------------------------------------
// Fused attention v5: Q64/K64, 4 waves, 2 blocks/CU (66.5 KB LDS).
// S/PV: 16x16x32 MFMA (wave owns 16 q-rows, intra-wave softmax).
// QD/KD: 32x32x16 MFMA, block-cooperative; q entirely in registers
// (A-frags for S, B-frags for QD). pe ring (128 slots) + incremental QD.
// ks/vT/pes: unpadded, XOR-swizzled, glds16-staged. ps aliases ks.
// QDs[l][slot] / KDs[r][di] pad 132 shorts: uint2 stores 8B-aligned,
// diagonal gathers conflict-free. hyp/mask prefetched during phase A.
// ---------------------------------------------------------------------------
__global__ __launch_bounds__(256, 2) void attn_mfma_kernel(
    const unsigned short* __restrict__ qw, const unsigned short* __restrict__ kw,
    const unsigned short* __restrict__ vtw, const unsigned short* __restrict__ peb,
    const float* __restrict__ hyp, const float* __restrict__ mask,
    float* __restrict__ out)
{
    __shared__ unsigned short ks[64 * 64];    // k [r][d] swizzled; aliased as ps
    __shared__ unsigned short vT[64 * 64];    // v^T [d][r] swizzled
    __shared__ unsigned short pes[128 * 64];  // pe ring [slot][d] swizzled
    __shared__ unsigned short QDs[64 * 132];  // [l][slot]
    __shared__ unsigned short KDs[64 * 132];  // [r][di_rel]

    const int t = threadIdx.x;
    const int lane = t & 63, w = t >> 6;
    const int l16 = lane & 15, quad = lane >> 4;
    const int l32 = lane & 31, h5 = lane >> 5;
    const int cs8 = lane & 7, r8 = lane >> 3;
    const int h = blockIdx.x, l0 = blockIdx.y * 64, b = blockIdx.z;

    const unsigned short* qb = qw + ((size_t)(b * NHEAD + h) * S_SEQ + l0) * HDIM;
    const unsigned short* kb = kw + (size_t)(b * NHEAD + h) * S_SEQ * HDIM;
    const unsigned short* vtb = vtw + (size_t)(b * NHEAD + h) * HDIM * S_SEQ;
    const float* hypb = hyp + (size_t)b * S_SEQ * S_SEQ;
    const float* maskb = mask + b * S_SEQ;

    // q fragments, loop-invariant, in registers.
    // A-frags (16x16x32): own 16 rows. B-frags (32x32x16): 2 l-groups x 4 k.
    const bf16x8 qfA0 = *(const bf16x8*)(qb + (16 * w + l16) * 64 + quad * 8);
    const bf16x8 qfA1 = *(const bf16x8*)(qb + (16 * w + l16) * 64 + 32 + quad * 8);
    bf16x8 qB[2][4];
#pragma unroll
    for (int lg = 0; lg < 2; ++lg)
#pragma unroll
        for (int f = 0; f < 4; ++f)
            qB[lg][f] = *(const bf16x8*)(qb + (32 * lg + l32) * 64 + 16 * f + 8 * h5);

    const int A0 = l0 + 960;     // abs pe row of window base at kt=0
    int sbase = A0 & 127;        // ring slot of window base (multiple of 64)

    // ---- prime: stage pe window-rel [64,128) and compute their QD ----
    {
        int pslot = (sbase + 64) & 127;
#pragma unroll
        for (int it = 0; it < 2; ++it) {
            int off = 16 * w + 8 * it + r8;
            int absr = A0 + 64 + off; if (absr > 2046) absr = 2046;
            glds16(peb + (size_t)absr * 64 + ((cs8 ^ (off & 7)) << 3),
                   &pes[(pslot + 16 * w + 8 * it) * 64]);
        }
    }
    __syncthreads();
    {
        int ddg = 2 + (w >> 1), lg = w & 1;
        f32x16 aQ;
#pragma unroll
        for (int e = 0; e < 16; ++e) aQ[e] = 0.f;
        int srow = (sbase + 32 * ddg + l32) & 127;
#pragma unroll
        for (int f = 0; f < 4; ++f) {
            int ch = 2 * f + h5;
            bf16x8 pA = *(bf16x8*)&pes[srow * 64 + ((ch ^ (srow & 7)) << 3)];
            aQ = __builtin_amdgcn_mfma_f32_32x32x16_bf16(pA, qB[lg][f], aQ, 0, 0, 0);
        }
        int colL = 32 * lg + l32;
#pragma unroll
        for (int q_ = 0; q_ < 4; ++q_) {
            int slot0 = (sbase + 32 * ddg + 8 * q_ + 4 * h5) & 127;
            uint2 o;
            o.x = pack2bf(aQ[4 * q_ + 0], aQ[4 * q_ + 1]);
            o.y = pack2bf(aQ[4 * q_ + 2], aQ[4 * q_ + 3]);
            *(uint2*)&QDs[colL * 132 + slot0] = o;
        }
    }

    f32x4 accO[4];
#pragma unroll
    for (int j = 0; j < 4; ++j) accO[j] = (f32x4){0.f, 0.f, 0.f, 0.f};
    float m_run[4], lsum[4];
#pragma unroll
    for (int i = 0; i < 4; ++i) { m_run[i] = -INFINITY; lsum[i] = 0.f; }

    for (int kt = 0; kt < 16; ++kt) {
        const int r0 = 64 * kt;
        const int pbase = A0 - r0;   // abs row of window-rel 0 (>= l0 >= 0)
        __syncthreads();   // prev C's ps/vT reads + prev A's old-pe reads done

        // ---- stage k, v^T, 64 new pe rows (glds16, swizzled) ----
#pragma unroll
        for (int it = 0; it < 2; ++it) {
            int row = 16 * w + 8 * it + r8;
            glds16(kb + (size_t)(r0 + row) * 64 + ((cs8 ^ (row & 7)) << 3),
                   &ks[(16 * w + 8 * it) * 64]);
            glds16(vtb + (size_t)row * 1024 + r0 + ((cs8 ^ (row & 7)) << 3),
                   &vT[(16 * w + 8 * it) * 64]);
            glds16(peb + (size_t)(pbase + row) * 64 + ((cs8 ^ (row & 7)) << 3),
                   &pes[(sbase + 16 * w + 8 * it) * 64]);
        }
        __syncthreads();

        // ---- hyp/mask prefetch (latency hidden behind phase A) ----
        float hv[4][4], mv[4];
#pragma unroll
        for (int j = 0; j < 4; ++j) {
            mv[j] = maskb[r0 + 16 * j + l16];
#pragma unroll
            for (int i = 0; i < 4; ++i)
                hv[i][j] = hypb[(size_t)(l0 + 16 * w + 4 * quad + i) * 1024 +
                                r0 + 16 * j + l16];
        }

        // ---- phase A: S (16x16), KD + QD (32x32) ----
        f32x4 accS[4];
#pragma unroll
        for (int j = 0; j < 4; ++j) {
            int row = 16 * j + l16;
            bf16x8 b0 = *(bf16x8*)&ks[row * 64 + ((quad ^ (row & 7)) << 3)];
            bf16x8 b1 = *(bf16x8*)&ks[row * 64 + (((quad + 4) ^ (row & 7)) << 3)];
            f32x4 a = (f32x4){0.f, 0.f, 0.f, 0.f};
            a = __builtin_amdgcn_mfma_f32_16x16x32_bf16(qfA0, b0, a, 0, 0, 0);
            a = __builtin_amdgcn_mfma_f32_16x16x32_bf16(qfA1, b1, a, 0, 0, 0);
            accS[j] = a;
        }
        {
            // KD: wave covers r-group (w>>1), di-groups {2*(w&1), 2*(w&1)+1}
            int rg = w >> 1;
            int rrow = 32 * rg + l32;
            bf16x8 kB[4];
#pragma unroll
            for (int f = 0; f < 4; ++f) {
                int ch = 2 * f + h5;
                kB[f] = *(bf16x8*)&ks[rrow * 64 + ((ch ^ (rrow & 7)) << 3)];
            }
#pragma unroll
            for (int dt = 0; dt < 2; ++dt) {
                int dig = 2 * (w & 1) + dt;
                f32x16 aK;
#pragma unroll
                for (int e = 0; e < 16; ++e) aK[e] = 0.f;
                int srow = (sbase + 32 * dig + l32) & 127;
#pragma unroll
                for (int f = 0; f < 4; ++f) {
                    int ch = 2 * f + h5;
                    bf16x8 pA = *(bf16x8*)&pes[srow * 64 + ((ch ^ (srow & 7)) << 3)];
                    aK = __builtin_amdgcn_mfma_f32_32x32x16_bf16(pA, kB[f], aK, 0, 0, 0);
                }
#pragma unroll
                for (int q_ = 0; q_ < 4; ++q_) {
                    int di0 = 32 * dig + 8 * q_ + 4 * h5;
                    uint2 o;
                    o.x = pack2bf(aK[4 * q_ + 0], aK[4 * q_ + 1]);
                    o.y = pack2bf(aK[4 * q_ + 2], aK[4 * q_ + 3]);
                    *(uint2*)&KDs[rrow * 132 + di0] = o;
                }
            }
        }
        {
            // QD for the 64 new diagonals (window-rel [0,64))
            int ddg = w >> 1, lg = w & 1;
            f32x16 aQ;
#pragma unroll
            for (int e = 0; e < 16; ++e) aQ[e] = 0.f;
            int srow = (sbase + 32 * ddg + l32) & 127;
#pragma unroll
            for (int f = 0; f < 4; ++f) {
                int ch = 2 * f + h5;
                bf16x8 pA = *(bf16x8*)&pes[srow * 64 + ((ch ^ (srow & 7)) << 3)];
                aQ = __builtin_amdgcn_mfma_f32_32x32x16_bf16(pA, qB[lg][f], aQ, 0, 0, 0);
            }
            int colL = 32 * lg + l32;
#pragma unroll
            for (int q_ = 0; q_ < 4; ++q_) {
                int slot0 = (sbase + 32 * ddg + 8 * q_ + 4 * h5) & 127;
                uint2 o;
                o.x = pack2bf(aQ[4 * q_ + 0], aQ[4 * q_ + 1]);
                o.y = pack2bf(aQ[4 * q_ + 2], aQ[4 * q_ + 3]);
                *(uint2*)&QDs[colL * 132 + slot0] = o;
            }
        }
        __syncthreads();

        // ---- phase B: diagonal gather + online softmax ----
        float sc[4][4], al[4];
#pragma unroll
        for (int j = 0; j < 4; ++j) {
            int r_loc = 16 * j + l16;
#pragma unroll
            for (int i = 0; i < 4; ++i) {
                int ll = 16 * w + 4 * quad + i;
                int di = ll - r_loc + 63;
                int slot = (sbase + di) & 127;
                float qd = bf2f(QDs[ll * 132 + slot]);
                float kd = bf2f(KDs[r_loc * 132 + di]);
                sc[i][j] = (accS[j][i] + qd + kd) * 0.125f + 0.5f * hv[i][j] + mv[j];
            }
        }
#pragma unroll
        for (int i = 0; i < 4; ++i) {
            float mx = fmaxf(fmaxf(sc[i][0], sc[i][1]), fmaxf(sc[i][2], sc[i][3]));
#pragma unroll
            for (int off = 1; off < 16; off <<= 1)
                mx = fmaxf(mx, __shfl_xor(mx, off));
            float m_new = fmaxf(m_run[i], mx);
            al[i] = __expf(m_run[i] - m_new);
            float rs = 0.f;
#pragma unroll
            for (int j = 0; j < 4; ++j) {
                float p = __expf(sc[i][j] - m_new);
                sc[i][j] = p;
                rs += p;
            }
#pragma unroll
            for (int off = 1; off < 16; off <<= 1)
                rs += __shfl_xor(rs, off);
            lsum[i] = lsum[i] * al[i] + rs;
            m_run[i] = m_new;
        }
        // probs (bf16, swizzled) into ps == ks alias; intra-wave rows
        {
            unsigned short* ps = ks;
#pragma unroll
            for (int i = 0; i < 4; ++i) {
                int ll = 16 * w + 4 * quad + i;
#pragma unroll
                for (int j = 0; j < 4; ++j) {
                    int r_loc = 16 * j + l16;
                    ps[ll * 64 + (((r_loc >> 3) ^ (ll & 7)) << 3) + (r_loc & 7)] =
                        f2bf(sc[i][j]);
                }
            }
        }

        // ---- phase C: PV (no barrier needed: rows intra-wave) ----
        {
            const unsigned short* ps = ks;
            int prow = 16 * w + l16;
            bf16x8 pf0 = *(bf16x8*)&ps[prow * 64 + ((quad ^ (prow & 7)) << 3)];
            bf16x8 pf1 = *(bf16x8*)&ps[prow * 64 + (((quad + 4) ^ (prow & 7)) << 3)];
#pragma unroll
            for (int jf = 0; jf < 4; ++jf) {
                int vrow = 16 * jf + l16;
                bf16x8 v0 = *(bf16x8*)&vT[vrow * 64 + ((quad ^ (vrow & 7)) << 3)];
                bf16x8 v1 = *(bf16x8*)&vT[vrow * 64 + (((quad + 4) ^ (vrow & 7)) << 3)];
                f32x4 o = accO[jf];
#pragma unroll
                for (int r = 0; r < 4; ++r) o[r] *= al[r];
                o = __builtin_amdgcn_mfma_f32_16x16x32_bf16(pf0, v0, o, 0, 0, 0);
                o = __builtin_amdgcn_mfma_f32_16x16x32_bf16(pf1, v1, o, 0, 0, 0);
                accO[jf] = o;
            }
        }
        sbase = (sbase + 64) & 127;
    }

    // ---- epilogue ----
#pragma unroll
    for (int jf = 0; jf < 4; ++jf)
#pragma unroll
        for (int i = 0; i < 4; ++i) {
            int ll = 16 * w + 4 * quad + i;
            out[((size_t)b * S_SEQ + l0 + ll) * 1024 + h * 64 + 16 * jf + l16] =
                accO[jf][i] / lsum[i];
        }
}

extern "C" void kernel_launch(void* const* d_in, const int* in_sizes, int n_in,
                              void* d_out, int out_size, void* d_ws, size_t ws_size,
                              hipStream_t stream) {
    const float* hs   = (const float*)d_in[0];
    const float* mask = (const float*)d_in[1];
    const float* hyp  = (const float*)d_in[2];
    const float* Wq   = (const float*)d_in[3];
    const float* bq   = (const float*)d_in[4];
    const float* Wk   = (const float*)d_in[5];
    const float* bk   = (const float*)d_in[6];
    const float* Wv   = (const float*)d_in[7];
    const float* bv   = (const float*)d_in[8];
    const float* de   = (const float*)d_in[9];

    char* ws = (char*)d_ws;
    unsigned short* qw  = (unsigned short*)(ws);                    // 8 MB
    unsigned short* kw  = (unsigned short*)(ws + (8u << 20));       // 8 MB
    unsigned short* vtw = (unsigned short*)(ws + (16u << 20));      // 8 MB (v^T)
    unsigned short* hsb = (unsigned short*)(ws + (24u << 20));      // 8 MB
    unsigned short* wt  = (unsigned short*)(ws + (32u << 20));      // 6 MB
    unsigned short* peb = (unsigned short*)(ws + (38u << 20));      // 0.25 MB

    conv_kernel<<<dim3((HS_F4 + PE_F4 + 255) / 256), 256, 0, stream>>>(hs, de, hsb, peb);
    wtrans_kernel<<<dim3(16, 16, 3), 256, 0, stream>>>(Wq, Wk, Wv, wt);
    qkv_mfma_kernel<<<dim3(8, 32, 3), 256, 0, stream>>>(hsb, wt, bq, bk, bv, qw, kw, vtw);
    attn_mfma_kernel<<<dim3(NHEAD, S_SEQ / 64, BATCH), 256, 0, stream>>>(
        qw, kw, vtw, peb, hyp, mask, (float*)d_out);
}